// Round 1
// baseline (4794.165 us; speedup 1.0000x reference)
//
#include <hip/hip_runtime.h>

#define T_DIM 256
#define B_DIM 128
#define C_DIM 512
#define H_DIM 512

typedef _Float16 half8 __attribute__((ext_vector_type(8)));
typedef float f32x4 __attribute__((ext_vector_type(4)));

__device__ __forceinline__ float sigf(float x) { return 1.0f / (1.0f + __expf(-x)); }
__device__ __forceinline__ float tanhf_(float x) {
  float e = __expf(2.0f * x);
  return (e - 1.0f) / (e + 1.0f);
}

__device__ __forceinline__ half8 cvt8(float4 a, float4 b) {
  half8 h;
  h[0] = (_Float16)a.x; h[1] = (_Float16)a.y; h[2] = (_Float16)a.z; h[3] = (_Float16)a.w;
  h[4] = (_Float16)b.x; h[5] = (_Float16)b.y; h[6] = (_Float16)b.z; h[7] = (_Float16)b.w;
  return h;
}

// ---------------- XCD-local barrier (unchanged, proven mechanism) ----------------
__device__ __forceinline__ void gbar_arrive(unsigned* slots, int bc, unsigned epoch) {
  __syncthreads();
  if (threadIdx.x == 0) *(volatile unsigned*)(slots + bc) = epoch;
}

__device__ __forceinline__ void gbar_wait(const unsigned* slots, unsigned epoch) {
  if (threadIdx.x < 64) {
    const volatile unsigned* myslot =
        (const volatile unsigned*)(slots + (threadIdx.x & 31));
    int guard = 0;
    for (;;) {
      asm volatile("buffer_inv sc0\n\ts_waitcnt vmcnt(0)" ::: "memory");
      unsigned v = *myslot;
      if (__ballot(v >= epoch) == ~0ull) break;
      if (++guard > (1 << 14)) break;  // fail loud, not dead
    }
  }
  __syncthreads();
  asm volatile("buffer_inv sc0" ::: "memory");
  asm volatile("s_waitcnt vmcnt(0)" ::: "memory");
}

// ---------------- cross-XCD (LLC) primitives ----------------
// Poll a single LLC flag until >= epoch. Closing inv sc0 sc1 drops stale L1+L2
// lines so subsequent PLAIN loads of producer data refetch from LLC (this is
// the gfx94x system-acquire lowering: buffer_inv sc0=1 sc1=1).
__device__ __forceinline__ void xpoll1(const unsigned* flag, unsigned epoch) {
  if (threadIdx.x < 64) {
    const volatile unsigned* f = (const volatile unsigned*)flag;
    int guard = 0;
    for (;;) {
      asm volatile("buffer_inv sc0 sc1\n\ts_waitcnt vmcnt(0)" ::: "memory");
      unsigned v = *f;
      if (__ballot(v >= epoch) == ~0ull) break;
      if (++guard > (1 << 15)) break;
    }
  }
  __syncthreads();
  asm volatile("buffer_inv sc0 sc1" ::: "memory");
  asm volatile("s_waitcnt vmcnt(0)" ::: "memory");
}

// Poll 32 LLC slots (producer-side back-pressure; no data read follows).
__device__ __forceinline__ void xpoll32(const unsigned* slots, unsigned epoch) {
  if (threadIdx.x < 64) {
    const volatile unsigned* my =
        (const volatile unsigned*)(slots + (threadIdx.x & 31));
    int guard = 0;
    for (;;) {
      asm volatile("buffer_inv sc0 sc1\n\ts_waitcnt vmcnt(0)" ::: "memory");
      unsigned v = *my;
      if (__ballot(v >= epoch) == ~0ull) break;
      if (++guard > (1 << 15)) break;
    }
  }
  __syncthreads();
}

// System-scope flag post: prior sc1 stores of THIS wave are ACKed at LLC by
// vmcnt(0); cross-block ordering is provided by the local barrier preceding it.
__device__ __forceinline__ void xpost(unsigned* flag, unsigned epoch) {
  asm volatile("s_waitcnt vmcnt(0)" ::: "memory");
  asm volatile("global_store_dword %0, %1, off sc0 sc1" ::
                   "v"(flag), "v"(epoch) : "memory");
}

// System-scope fp16 store (write-through past local L2 to LLC).
__device__ __forceinline__ void store_llc_h16(_Float16* p, _Float16 v) {
  unsigned u = (unsigned)__builtin_bit_cast(unsigned short, v);
  asm volatile("global_store_short %0, %1, off sc0 sc1" ::
                   "v"(p), "v"(u) : "memory");
}

// Layer-pipelined persistent nested-LSTM.
// Grid 256x256, 1 block/CU. XCD = blockIdx&7; layer = xcd>>2 (XCDs 0-3 run
// layer 0, 4-7 run layer 1 CONCURRENTLY, 1-step skewed). pgrp = xcd&3 owns
// batch rows [32*pgrp, 32*pgrp+32) (M=32 -> two 16-row m-tiles/block); block
// bc = blockIdx>>3 owns gate cols [16bc,16bc+16). K-SPLIT unchanged: wave wv
// holds fp16 B-frags of all 4 gates for K-slice [256wv,+256) = 256 VGPRs.
// LDS 64KB: A-tile 32ks x 2KB fragment-linear; Pl (32KB partials) OVERLAYS
// ks0..15 (extra syncthreads between MFMA A-reads and Pl writes).
// Intra-layer exchange (h, hi, cell): XCD-local slabs, plain stores +
// buffer_inv sc0 barriers (identical protocol to the previous kernel).
// Cross-layer y0 = layer-0 h: parity-ping-pong slab in LLC written with
// sc0|sc1 stores; single fwd flag/pair posted by bc0 after L0's local end
// barrier (all 32 blocks' stores ACKed); 32 back slots bound L0's lead (<=3
// steps) so the 2-deep parity buffer is safe. L1 stages y0 inside its end
// barrier poll window (LLC latency overlaps straggler wait).
__global__ __launch_bounds__(256, 1) void nlstm_pipe(
    const float* __restrict__ xin, const float* __restrict__ h0,
    const float* __restrict__ Wg, const float* __restrict__ bgb,
    const float* __restrict__ Wi, const float* __restrict__ bib,
    float* __restrict__ out, unsigned* __restrict__ bar,
    _Float16* __restrict__ y0buf, _Float16* __restrict__ hlcb,
    _Float16* __restrict__ hicb, _Float16* __restrict__ clcb)
{
  __shared__ __align__(16) char smem[65536];
  _Float16* AldsH = (_Float16*)smem;  // 32 ks x 1024 halfs
  float* Pl = (float*)smem;           // overlay on ks0..15 (32KB)

  const int tid  = threadIdx.x;
  const int xcd  = blockIdx.x & 7;
  const int lyr  = xcd >> 2;          // 0: XCDs 0-3, 1: XCDs 4-7
  const int pgrp = xcd & 3;           // pair group (batch-row group)
  const int bc   = blockIdx.x >> 3;   // 0..31 col-block
  const int wv   = tid >> 6;
  const int lane = tid & 63;
  const int ln   = lane & 15;
  const int kg   = lane >> 4;
  const int pb   = tid >> 4;          // 0..15
  const int pj   = tid & 15;
  const int jglob = bc * 16 + pj;
  const int ncol  = bc * 16 + ln;
  const int r0    = pgrp * 32;        // batch-row base

  // fragment-order offset of (local row = pb + 16*mt, col = jglob); +mt*512
  const int exo = (jglob >> 5) * 1024 + (((jglob >> 3) & 3) * 16 + pb) * 8 + (jglob & 7);

  unsigned* eslots = bar + xcd * 64;        // 32 end slots
  unsigned* cslots = eslots + 32;           // 32 cell slots
  unsigned* fwdF = bar + 512 + pgrp * 16;   // single fwd flag per pair
  unsigned* bakF = bar + 576 + pgrp * 32;   // 32 back slots per pair

  _Float16* hloc0 = hlcb + ((size_t)xcd * 2 + 0) * 16384;
  _Float16* hloc1 = hlcb + ((size_t)xcd * 2 + 1) * 16384;
  _Float16* hilc0 = hicb + ((size_t)xcd * 2 + 0) * 16384;
  _Float16* hilc1 = hicb + ((size_t)xcd * 2 + 1) * 16384;
  _Float16* cbase = clcb + (size_t)xcd * 16384;
  _Float16* y0s0 = y0buf + ((size_t)pgrp * 2 + 0) * 16384;
  _Float16* y0s1 = y0buf + ((size_t)pgrp * 2 + 1) * 16384;

  // ---- weights -> VGPR fp16 frags (fixed layer for this block) ----
  half8 wgf[4][8], wif[4][8];
  float bgv[4], biv[4];
#pragma unroll
  for (int g = 0; g < 4; ++g) {
    const float* wgr = Wg + ((size_t)lyr * 2048 + g * 512 + ncol) * 1024 + wv * 256;
    const float* wir = Wi + ((size_t)lyr * 2048 + g * 512 + ncol) * 1024 + wv * 256;
#pragma unroll
    for (int i = 0; i < 8; ++i) {
      const float* p = wgr + i * 32 + kg * 8;
      wgf[g][i] = cvt8(*(const float4*)p, *(const float4*)(p + 4));
      const float* q = wir + i * 32 + kg * 8;
      wif[g][i] = cvt8(*(const float4*)q, *(const float4*)(q + 4));
    }
    bgv[g] = bgb[lyr * 2048 + g * 512 + jglob];
    biv[g] = bib[lyr * 2048 + g * 512 + jglob];
  }

  // ---- initial states (rows pb, pb+16) ----
  float st_c[2], st_ci[2], o_pre[2];
  {
    const float* h0l = h0 + (size_t)lyr * 4 * B_DIM * H_DIM + (size_t)(r0 + pb) * H_DIM + jglob;
#pragma unroll
    for (int mt = 0; mt < 2; ++mt) {
      const float* pp = h0l + (size_t)mt * 16 * H_DIM;
      float h_in  = pp[0];
      st_c[mt]    = pp[(size_t)1 * B_DIM * H_DIM];
      float hi_in = pp[(size_t)2 * B_DIM * H_DIM];
      st_ci[mt]   = pp[(size_t)3 * B_DIM * H_DIM];
      hloc0[exo + mt * 512] = (_Float16)h_in;   // parity 0, read at t=0
      hilc0[exo + mt * 512] = (_Float16)hi_in;
      o_pre[mt] = 0.f;
    }
  }

  // ---- helpers ----
  auto stage_x = [&](int t) {  // layer 0 only: xin(t) -> ks0..15
    const int m = tid & 31;
    const int q = tid >> 5;  // 0..7
    const int mt = m >> 4, mm = m & 15;
    const float* srow = xin + ((size_t)t * B_DIM + r0 + m) * C_DIM;
#pragma unroll
    for (int i = 0; i < 8; ++i) {
      const int chunk = q * 8 + i;  // 0..63 (8-float groups)
      const int ks = chunk >> 2, kq = chunk & 3;
      const float* p = srow + chunk * 8;
      *(half8*)(AldsH + ks * 1024 + mt * 512 + (kq * 16 + mm) * 8) =
          cvt8(*(const float4*)p, *(const float4*)(p + 4));
    }
  };
  auto copy_slab = [&](int dstHalfBase, const _Float16* src) {  // 32KB copy
#pragma unroll
    for (int i = 0; i < 8; ++i) {
      const int idx = i * 256 + tid;
      *(uint4*)(AldsH + dstHalfBase + idx * 8) = *(const uint4*)(src + idx * 8);
    }
  };
  auto gemm = [&](half8 (&wf)[4][8]) {  // A(32x1024) @ W^T, partials -> Pl
    f32x4 acc[2][4];
#pragma unroll
    for (int mt = 0; mt < 2; ++mt)
#pragma unroll
      for (int g = 0; g < 4; ++g) acc[mt][g] = (f32x4){0.f, 0.f, 0.f, 0.f};
#pragma unroll
    for (int i = 0; i < 8; ++i) {
      const _Float16* ab = AldsH + (wv * 8 + i) * 1024 + lane * 8;
      half8 a0 = *(const half8*)(ab);
      half8 a1 = *(const half8*)(ab + 512);
#pragma unroll
      for (int g = 0; g < 4; ++g) {
        acc[0][g] = __builtin_amdgcn_mfma_f32_16x16x32_f16(a0, wf[g][i], acc[0][g], 0, 0, 0);
        acc[1][g] = __builtin_amdgcn_mfma_f32_16x16x32_f16(a1, wf[g][i], acc[1][g], 0, 0, 0);
      }
    }
    __syncthreads();  // all A reads done before Pl overlays ks0..15
#pragma unroll
    for (int mt = 0; mt < 2; ++mt)
#pragma unroll
      for (int g = 0; g < 4; ++g)
#pragma unroll
        for (int rr = 0; rr < 4; ++rr)
          Pl[(((g * 2 + mt) * 16 + kg * 4 + rr) * 16 + ln) * 4 + (wv ^ kg)] = acc[mt][g][rr];
    __syncthreads();
  };
  auto plsum = [&](int g, int mt) -> float {
    f32x4 v = *(const f32x4*)(Pl + (((g * 2 + mt) * 16 + pb) * 16 + pj) * 4);
    return v[0] + v[1] + v[2] + v[3];
  };

  unsigned eseq = 0, cseq = 0;

  // ---- init publish (local) + x(0) staging ----
  gbar_arrive(eslots, bc, ++eseq);
  if (lyr == 0) stage_x(0);  // inside poll window
  gbar_wait(eslots, eseq);
  if (lyr == 1) {
    // initial x(0) = y0(0): wait for L0 step 0, then plain-copy post-inv
    xpoll1(fwdF, 1u);
    copy_slab(0, y0s1);  // parity (0+1)&1 = 1
    __syncthreads();
    if (tid == 0) xpost(bakF + bc, 1u);  // consumed y0(0)
  }

  for (int t = 0; t < T_DIM; ++t) {
    const int pr = t & 1;
    _Float16* hrd  = pr ? hloc1 : hloc0;  // h(t-1)
    _Float16* hwr  = pr ? hloc0 : hloc1;  // h(t)
    _Float16* hird = pr ? hilc1 : hilc0;  // hi(t-1)
    _Float16* hiwr = pr ? hilc0 : hilc1;  // hi(t)
    _Float16* y0wr = pr ? y0s0 : y0s1;    // parity (t+1)&1
    _Float16* y0rd = pr ? y0s1 : y0s0;    // parity t&1 (x(t+1) in end window)

    // L0 back-pressure: before overwriting y0 parity (t+1)&1 (= h(t-2)),
    // all 32 L1 blocks must have consumed it (back >= t-1).
    if (lyr == 0 && t >= 2) xpoll32(bakF, (unsigned)(t - 1));

    // ---- stage own h(t-1) -> ks16..31 (x already resident in ks0..15) ----
    copy_slab(16384, hrd);
    __syncthreads();

    gemm(wgf);  // MFMA 1: [x | h] @ Wg^T

    // ---- pointwise 1: cell = sig(f)*c + sig(i)*tanh(gc) ----
#pragma unroll
    for (int mt = 0; mt < 2; ++mt) {
      float gi = plsum(0, mt) + bgv[0];
      float gf = plsum(1, mt) + bgv[1];
      float go = plsum(2, mt) + bgv[2];
      float gc = plsum(3, mt) + bgv[3];
      float cell = sigf(gf) * st_c[mt] + sigf(gi) * tanhf_(gc);
      o_pre[mt] = go;
      cbase[exo + mt * 512] = (_Float16)cell;
    }
    gbar_arrive(cslots, bc, ++cseq);  // cell barrier: arrive
    copy_slab(16384, hird);           // prestage hi(t-1) inside poll window
    gbar_wait(cslots, cseq);          // cell visible XCD-wide

    copy_slab(0, cbase);              // stage cell -> ks0..15 (over Pl)
    __syncthreads();

    gemm(wif);  // MFMA 2: [cell | hi] @ Wi^T

    // ---- pointwise 2: inner cell; outputs; c := hi_n ----
#pragma unroll
    for (int mt = 0; mt < 2; ++mt) {
      float i2 = plsum(0, mt) + biv[0];
      float f2 = plsum(1, mt) + biv[1];
      float o2 = plsum(2, mt) + biv[2];
      float c2 = plsum(3, mt) + biv[3];
      float ci_n = sigf(f2) * st_ci[mt] + sigf(i2) * tanhf_(c2);
      float hi_n = sigf(o2) * tanhf_(ci_n);
      float h_n  = sigf(o_pre[mt]) * tanhf_(hi_n);
      st_ci[mt] = ci_n;
      st_c[mt]  = hi_n;  // reference carry: c <- hi_n
      hiwr[exo + mt * 512] = (_Float16)hi_n;
      hwr[exo + mt * 512]  = (_Float16)h_n;
      if (lyr == 0) {
        store_llc_h16(y0wr + exo + mt * 512, (_Float16)h_n);  // cross-layer feed
      } else {
        out[((size_t)t * B_DIM + (r0 + pb + mt * 16)) * H_DIM + jglob] = h_n;
      }
    }

    gbar_arrive(eslots, bc, ++eseq);  // end barrier: arrive
    if (lyr == 0) {
      if (t + 1 < T_DIM) stage_x(t + 1);  // prestage xin(t+1) in poll window
    } else if (t + 1 < T_DIM) {
      // stage x(t+1) = y0(t+1) in poll window: needs L0 done with step t+1
      xpoll1(fwdF, (unsigned)(t + 2));
      copy_slab(0, y0rd);
      __syncthreads();
      if (tid == 0) xpost(bakF + bc, (unsigned)(t + 2));  // consumed y0(t+1)
    }
    gbar_wait(eslots, eseq);  // h/hi visible for next step
    // fwd post after end-wait: all 32 L0 blocks' y0 sc1-stores are ACKed
    if (lyr == 0 && tid == 0 && bc == 0) xpost(fwdF, (unsigned)(t + 1));
  }
}

extern "C" void kernel_launch(void* const* d_in, const int* in_sizes, int n_in,
                              void* d_out, int out_size, void* d_ws, size_t ws_size,
                              hipStream_t stream) {
  const float* xin = (const float*)d_in[0];
  const float* h0  = (const float*)d_in[1];
  const float* Wg  = (const float*)d_in[2];
  const float* bg  = (const float*)d_in[3];
  const float* Wi  = (const float*)d_in[4];
  const float* bi  = (const float*)d_in[5];
  float* out = (float*)d_out;

  // ws layout:
  //   [0, 4KB)  flags: 8 XCD x 64 local slots (2KB) | fwd 4x16 | back 4x32
  //   y0buf  [4 pair][2 parity][16384] fp16 = 256KB   (LLC cross-layer feed)
  //   hlcb   [8 xcd][2 parity][16384] fp16 = 512KB    (local h slabs)
  //   hicb   [8 xcd][2 parity][16384] fp16 = 512KB    (local hi slabs)
  //   clcb   [8 xcd][16384] fp16 = 256KB              (local cell slabs)
  // total ~1.54MB
  unsigned* bar  = (unsigned*)d_ws;
  _Float16* y0b  = (_Float16*)((char*)d_ws + 4096);
  _Float16* hlcb = y0b + (size_t)4 * 2 * 16384;
  _Float16* hicb = hlcb + (size_t)8 * 2 * 16384;
  _Float16* clcb = hicb + (size_t)8 * 2 * 16384;

  hipMemsetAsync(d_ws, 0, 4096, stream);  // all flag epochs start at 0

  nlstm_pipe<<<dim3(256), dim3(256), 0, stream>>>(
      xin, h0, Wg, bg, Wi, bi, out, bar, y0b, hlcb, hicb, clcb);
}

// Round 2
// 2695.106 us; speedup vs baseline: 1.7788x; 1.7788x over previous
//
#include <hip/hip_runtime.h>

#define T_DIM 256
#define B_DIM 128
#define C_DIM 512
#define H_DIM 512

typedef _Float16 half8 __attribute__((ext_vector_type(8)));
typedef float f32x4 __attribute__((ext_vector_type(4)));
typedef unsigned u32x4 __attribute__((ext_vector_type(4)));

__device__ __forceinline__ float sigf(float x) { return 1.0f / (1.0f + __expf(-x)); }
__device__ __forceinline__ float tanhf_(float x) {
  float e = __expf(2.0f * x);
  return (e - 1.0f) / (e + 1.0f);
}

__device__ __forceinline__ half8 cvt8(float4 a, float4 b) {
  half8 h;
  h[0] = (_Float16)a.x; h[1] = (_Float16)a.y; h[2] = (_Float16)a.z; h[3] = (_Float16)a.w;
  h[4] = (_Float16)b.x; h[5] = (_Float16)b.y; h[6] = (_Float16)b.z; h[7] = (_Float16)b.w;
  return h;
}

// ---------------- XCD-local barrier (unchanged, proven) ----------------
__device__ __forceinline__ void gbar_arrive(unsigned* slots, int bc, unsigned epoch) {
  __syncthreads();
  if (threadIdx.x == 0) *(volatile unsigned*)(slots + bc) = epoch;
}

__device__ __forceinline__ void gbar_wait(const unsigned* slots, unsigned epoch) {
  if (threadIdx.x < 64) {
    const volatile unsigned* myslot =
        (const volatile unsigned*)(slots + (threadIdx.x & 31));
    int guard = 0;
    for (;;) {
      asm volatile("buffer_inv sc0\n\ts_waitcnt vmcnt(0)" ::: "memory");
      unsigned v = *myslot;
      if (__ballot(v >= epoch) == ~0ull) break;
      if (++guard > (1 << 14)) break;  // fail loud, not dead
    }
  }
  __syncthreads();
  asm volatile("buffer_inv sc0" ::: "memory");      // L1-only inv; never touches L2
  asm volatile("s_waitcnt vmcnt(0)" ::: "memory");
}

// ---------------- cross-XCD (LLC) primitives — NO cache invalidation ----------------
// System-scope load: sc0|sc1 bypasses L1 AND the (non-coherent) XCD L2, reading
// the LLC coherence point directly. Poll loops built on this leave both caches
// intact (R1's buffer_inv sc0 sc1 polls wiped the whole XCD L2 every iteration,
// degrading the L2-resident local exchange slabs to LLC misses: the regression).
__device__ __forceinline__ unsigned sysld_u32(const unsigned* p) {
  unsigned v;
  asm volatile("global_load_dword %0, %1, off sc0 sc1\n\ts_waitcnt vmcnt(0)"
               : "=v"(v) : "v"(p) : "memory");
  return v;
}

// Poll 32 LLC slots (2 lanes/slot) until all >= epoch.
__device__ __forceinline__ void xpollsys(const unsigned* slots, unsigned epoch) {
  if (threadIdx.x < 64) {
    const unsigned* my = slots + (threadIdx.x & 31);
    int guard = 0;
    for (;;) {
      unsigned v = sysld_u32(my);
      if (__ballot(v >= epoch) == ~0ull) break;
      if (++guard > (1 << 15)) break;  // fail loud, not dead
    }
  }
  __syncthreads();
}

// System-scope flag post: prior sc1 stores of this wave ACKed at LLC by vmcnt(0).
__device__ __forceinline__ void xpost(unsigned* flag, unsigned epoch) {
  asm volatile("s_waitcnt vmcnt(0)" ::: "memory");
  asm volatile("global_store_dword %0, %1, off sc0 sc1" ::
                   "v"(flag), "v"(epoch) : "memory");
}

// System-scope fp16 store (write-through past local L2 to LLC).
__device__ __forceinline__ void store_llc_h16(_Float16* p, _Float16 v) {
  unsigned u = (unsigned)__builtin_bit_cast(unsigned short, v);
  asm volatile("global_store_short %0, %1, off sc0 sc1" ::
                   "v"(p), "v"(u) : "memory");
}

// Layer-pipelined persistent nested-LSTM (same schedule as R1, which passed
// correctness; only the cross-XCD primitives and flag topology changed).
// Grid 256x256, 1 block/CU. XCD = blockIdx&7; layer = xcd>>2 (XCDs 0-3 run
// layer 0, XCDs 4-7 layer 1 concurrently, 1-2 steps skewed). pgrp = xcd&3 owns
// batch rows [32*pgrp,+32) (two 16-row m-tiles); bc = blockIdx>>3 owns gate
// cols [16bc,+16). K-SPLIT: wave wv holds fp16 B-frags for K-slice [256wv,+256).
// LDS 64KB: A-tile 32ks x 2KB fragment-linear; Pl partials (32KB) overlay
// ks0..15. Intra-layer exchange: XCD-local slabs + sc0-only barriers (proven).
// Cross-layer y0: parity-ping-pong LLC slab, sc0|sc1 stores; 32 per-block fwd
// slots posted at each L0 block's end-ARRIVE (syncthreads already drained its
// y0 stores) -> no dependence on any block's barrier-exit; L1 polls/copies with
// system loads inside its end window; 32 back slots bound L0's lead to <=2.
__global__ __launch_bounds__(256, 1) void nlstm_pipe(
    const float* __restrict__ xin, const float* __restrict__ h0,
    const float* __restrict__ Wg, const float* __restrict__ bgb,
    const float* __restrict__ Wi, const float* __restrict__ bib,
    float* __restrict__ out, unsigned* __restrict__ bar,
    _Float16* __restrict__ y0buf, _Float16* __restrict__ hlcb,
    _Float16* __restrict__ hicb, _Float16* __restrict__ clcb)
{
  __shared__ __align__(16) char smem[65536];
  _Float16* AldsH = (_Float16*)smem;  // 32 ks x 1024 halfs
  float* Pl = (float*)smem;           // overlay on ks0..15 (32KB)

  const int tid  = threadIdx.x;
  const int xcd  = blockIdx.x & 7;
  const int lyr  = xcd >> 2;
  const int pgrp = xcd & 3;
  const int bc   = blockIdx.x >> 3;
  const int wv   = tid >> 6;
  const int lane = tid & 63;
  const int ln   = lane & 15;
  const int kg   = lane >> 4;
  const int pb   = tid >> 4;
  const int pj   = tid & 15;
  const int jglob = bc * 16 + pj;
  const int ncol  = bc * 16 + ln;
  const int r0    = pgrp * 32;

  const int exo = (jglob >> 5) * 1024 + (((jglob >> 3) & 3) * 16 + pb) * 8 + (jglob & 7);

  unsigned* eslots = bar + xcd * 64;       // 32 end slots (local)
  unsigned* cslots = eslots + 32;          // 32 cell slots (local)
  unsigned* fwdS = bar + 512 + pgrp * 32;  // 32 per-block fwd slots (LLC)
  unsigned* bakS = bar + 640 + pgrp * 32;  // 32 per-block back slots (LLC)

  _Float16* hloc0 = hlcb + ((size_t)xcd * 2 + 0) * 16384;
  _Float16* hloc1 = hlcb + ((size_t)xcd * 2 + 1) * 16384;
  _Float16* hilc0 = hicb + ((size_t)xcd * 2 + 0) * 16384;
  _Float16* hilc1 = hicb + ((size_t)xcd * 2 + 1) * 16384;
  _Float16* cbase = clcb + (size_t)xcd * 16384;
  _Float16* y0s0 = y0buf + ((size_t)pgrp * 2 + 0) * 16384;
  _Float16* y0s1 = y0buf + ((size_t)pgrp * 2 + 1) * 16384;

  // ---- weights -> VGPR fp16 frags ----
  half8 wgf[4][8], wif[4][8];
  float bgv[4], biv[4];
#pragma unroll
  for (int g = 0; g < 4; ++g) {
    const float* wgr = Wg + ((size_t)lyr * 2048 + g * 512 + ncol) * 1024 + wv * 256;
    const float* wir = Wi + ((size_t)lyr * 2048 + g * 512 + ncol) * 1024 + wv * 256;
#pragma unroll
    for (int i = 0; i < 8; ++i) {
      const float* p = wgr + i * 32 + kg * 8;
      wgf[g][i] = cvt8(*(const float4*)p, *(const float4*)(p + 4));
      const float* q = wir + i * 32 + kg * 8;
      wif[g][i] = cvt8(*(const float4*)q, *(const float4*)(q + 4));
    }
    bgv[g] = bgb[lyr * 2048 + g * 512 + jglob];
    biv[g] = bib[lyr * 2048 + g * 512 + jglob];
  }

  // ---- initial states (rows pb, pb+16) ----
  float st_c[2], st_ci[2], o_pre[2];
  {
    const float* h0l = h0 + (size_t)lyr * 4 * B_DIM * H_DIM + (size_t)(r0 + pb) * H_DIM + jglob;
#pragma unroll
    for (int mt = 0; mt < 2; ++mt) {
      const float* pp = h0l + (size_t)mt * 16 * H_DIM;
      float h_in  = pp[0];
      st_c[mt]    = pp[(size_t)1 * B_DIM * H_DIM];
      float hi_in = pp[(size_t)2 * B_DIM * H_DIM];
      st_ci[mt]   = pp[(size_t)3 * B_DIM * H_DIM];
      hloc0[exo + mt * 512] = (_Float16)h_in;
      hilc0[exo + mt * 512] = (_Float16)hi_in;
      o_pre[mt] = 0.f;
    }
  }

  // ---- helpers ----
  auto stage_x = [&](int t) {  // layer 0 only: xin(t) -> ks0..15
    const int m = tid & 31;
    const int q = tid >> 5;
    const int mt = m >> 4, mm = m & 15;
    const float* srow = xin + ((size_t)t * B_DIM + r0 + m) * C_DIM;
#pragma unroll
    for (int i = 0; i < 8; ++i) {
      const int chunk = q * 8 + i;
      const int ks = chunk >> 2, kq = chunk & 3;
      const float* p = srow + chunk * 8;
      *(half8*)(AldsH + ks * 1024 + mt * 512 + (kq * 16 + mm) * 8) =
          cvt8(*(const float4*)p, *(const float4*)(p + 4));
    }
  };
  auto copy_slab = [&](int dstHalfBase, const _Float16* src) {  // local 32KB copy
#pragma unroll
    for (int i = 0; i < 8; ++i) {
      const int idx = i * 256 + tid;
      *(u32x4*)(AldsH + dstHalfBase + idx * 8) = *(const u32x4*)(src + idx * 8);
    }
  };
  auto copy_slab_sys = [&](int dstHalfBase, const _Float16* src) {  // LLC 32KB copy
    u32x4 v[8];
#pragma unroll
    for (int i = 0; i < 8; ++i) {
      const u32x4* p = (const u32x4*)(src + (i * 256 + tid) * 8);
      asm volatile("global_load_dwordx4 %0, %1, off sc0 sc1"
                   : "=v"(v[i]) : "v"(p) : "memory");
    }
    asm volatile("s_waitcnt vmcnt(0)" ::: "memory");
    __builtin_amdgcn_sched_barrier(0);
#pragma unroll
    for (int i = 0; i < 8; ++i)
      *(u32x4*)(AldsH + dstHalfBase + (i * 256 + tid) * 8) = v[i];
  };
  auto gemm = [&](half8 (&wf)[4][8]) {
    f32x4 acc[2][4];
#pragma unroll
    for (int mt = 0; mt < 2; ++mt)
#pragma unroll
      for (int g = 0; g < 4; ++g) acc[mt][g] = (f32x4){0.f, 0.f, 0.f, 0.f};
#pragma unroll
    for (int i = 0; i < 8; ++i) {
      const _Float16* ab = AldsH + (wv * 8 + i) * 1024 + lane * 8;
      half8 a0 = *(const half8*)(ab);
      half8 a1 = *(const half8*)(ab + 512);
#pragma unroll
      for (int g = 0; g < 4; ++g) {
        acc[0][g] = __builtin_amdgcn_mfma_f32_16x16x32_f16(a0, wf[g][i], acc[0][g], 0, 0, 0);
        acc[1][g] = __builtin_amdgcn_mfma_f32_16x16x32_f16(a1, wf[g][i], acc[1][g], 0, 0, 0);
      }
    }
    __syncthreads();  // all A reads done before Pl overlays ks0..15
#pragma unroll
    for (int mt = 0; mt < 2; ++mt)
#pragma unroll
      for (int g = 0; g < 4; ++g)
#pragma unroll
        for (int rr = 0; rr < 4; ++rr)
          Pl[(((g * 2 + mt) * 16 + kg * 4 + rr) * 16 + ln) * 4 + (wv ^ kg)] = acc[mt][g][rr];
    __syncthreads();
  };
  auto plsum = [&](int g, int mt) -> float {
    f32x4 v = *(const f32x4*)(Pl + (((g * 2 + mt) * 16 + pb) * 16 + pj) * 4);
    return v[0] + v[1] + v[2] + v[3];
  };

  unsigned eseq = 0, cseq = 0;

  // ---- init publish (local) + x(0)/y0(0) staging ----
  gbar_arrive(eslots, bc, ++eseq);
  if (lyr == 0) stage_x(0);
  gbar_wait(eslots, eseq);
  if (lyr == 1) {
    xpollsys(fwdS, 1u);        // all 32 L0 blocks finished step 0
    copy_slab_sys(0, y0s1);    // y0(0) lives in parity-1 slab
    __syncthreads();
    if (tid == 0) xpost(bakS + bc, 1u);  // consumed y0(0)
  }

  for (int t = 0; t < T_DIM; ++t) {
    const int pr = t & 1;
    _Float16* hrd  = pr ? hloc1 : hloc0;
    _Float16* hwr  = pr ? hloc0 : hloc1;
    _Float16* hird = pr ? hilc1 : hilc0;
    _Float16* hiwr = pr ? hilc0 : hilc1;
    _Float16* y0wr = pr ? y0s0 : y0s1;  // L0 step t writes slab (t+1)&1
    _Float16* y0rd = pr ? y0s1 : y0s0;  // L1 end window stages slab t&1 = y0(t+1)

    // ---- stage own h(t-1) -> ks16..31 (x/y0 already resident in ks0..15) ----
    copy_slab(16384, hrd);
    __syncthreads();

    gemm(wgf);  // MFMA 1: [x | h] @ Wg^T

#pragma unroll
    for (int mt = 0; mt < 2; ++mt) {
      float gi = plsum(0, mt) + bgv[0];
      float gf = plsum(1, mt) + bgv[1];
      float go = plsum(2, mt) + bgv[2];
      float gc = plsum(3, mt) + bgv[3];
      float cell = sigf(gf) * st_c[mt] + sigf(gi) * tanhf_(gc);
      o_pre[mt] = go;
      cbase[exo + mt * 512] = (_Float16)cell;
    }
    gbar_arrive(cslots, bc, ++cseq);
    copy_slab(16384, hird);   // prestage hi(t-1) inside poll window
    gbar_wait(cslots, cseq);  // cell visible XCD-wide

    copy_slab(0, cbase);      // stage cell -> ks0..15 (over Pl)
    __syncthreads();

    gemm(wif);  // MFMA 2: [cell | hi] @ Wi^T

#pragma unroll
    for (int mt = 0; mt < 2; ++mt) {
      float i2 = plsum(0, mt) + biv[0];
      float f2 = plsum(1, mt) + biv[1];
      float o2 = plsum(2, mt) + biv[2];
      float c2 = plsum(3, mt) + biv[3];
      float ci_n = sigf(f2) * st_ci[mt] + sigf(i2) * tanhf_(c2);
      float hi_n = sigf(o2) * tanhf_(ci_n);
      float h_n  = sigf(o_pre[mt]) * tanhf_(hi_n);
      st_ci[mt] = ci_n;
      st_c[mt]  = hi_n;  // reference carry: c <- hi_n
      hiwr[exo + mt * 512] = (_Float16)hi_n;
      hwr[exo + mt * 512]  = (_Float16)h_n;
      if (lyr == 0) {
        store_llc_h16(y0wr + exo + mt * 512, (_Float16)h_n);
      } else {
        out[((size_t)t * B_DIM + (r0 + pb + mt * 16)) * H_DIM + jglob] = h_n;
      }
    }

    gbar_arrive(eslots, bc, ++eseq);  // end barrier: arrive (drains y0 stores)
    if (lyr == 0) {
      // fwd post FIRST: unblocks L1 without waiting for any barrier-exit.
      if (tid == 0) xpost(fwdS + bc, (unsigned)(t + 1));
      if (t + 1 < T_DIM) stage_x(t + 1);  // prestage xin(t+1) in poll window
      // clearance for step t+1's slab ((t+2)&1, holds y0(t-1)): all L1 blocks
      // must have consumed it (bak >= t). Overlapped with end-poll window.
      if (t >= 1 && t + 1 < T_DIM) xpollsys(bakS, (unsigned)t);
    } else if (t + 1 < T_DIM) {
      // stage x(t+1) = y0(t+1) in poll window: needs all L0 blocks past t+1
      xpollsys(fwdS, (unsigned)(t + 2));
      copy_slab_sys(0, y0rd);
      __syncthreads();
      if (tid == 0) xpost(bakS + bc, (unsigned)(t + 2));  // consumed y0(t+1)
    }
    gbar_wait(eslots, eseq);  // h/hi visible for next step
  }
}

extern "C" void kernel_launch(void* const* d_in, const int* in_sizes, int n_in,
                              void* d_out, int out_size, void* d_ws, size_t ws_size,
                              hipStream_t stream) {
  const float* xin = (const float*)d_in[0];
  const float* h0  = (const float*)d_in[1];
  const float* Wg  = (const float*)d_in[2];
  const float* bg  = (const float*)d_in[3];
  const float* Wi  = (const float*)d_in[4];
  const float* bi  = (const float*)d_in[5];
  float* out = (float*)d_out;

  // ws layout:
  //   [0,4KB)  flags: 8 XCD x 64 local (2KB) | fwd 4x32 @ +512 | back 4x32 @ +640
  //   y0buf  [4 pair][2 parity][16384] fp16 = 256KB  (LLC cross-layer feed)
  //   hlcb   [8 xcd][2 parity][16384] fp16 = 512KB
  //   hicb   [8 xcd][2 parity][16384] fp16 = 512KB
  //   clcb   [8 xcd][16384] fp16 = 256KB
  unsigned* bar  = (unsigned*)d_ws;
  _Float16* y0b  = (_Float16*)((char*)d_ws + 4096);
  _Float16* hlcb = y0b + (size_t)4 * 2 * 16384;
  _Float16* hicb = hlcb + (size_t)8 * 2 * 16384;
  _Float16* clcb = hicb + (size_t)8 * 2 * 16384;

  hipMemsetAsync(d_ws, 0, 4096, stream);  // all flag epochs start at 0

  nlstm_pipe<<<dim3(256), dim3(256), 0, stream>>>(
      xin, h0, Wg, bg, Wi, bi, out, bar, y0b, hlcb, hicb, clcb);
}

// Round 3
// 2411.507 us; speedup vs baseline: 1.9880x; 1.1176x over previous
//
#include <hip/hip_runtime.h>

#define T_DIM 256
#define B_DIM 128
#define C_DIM 512
#define H_DIM 512

// LDS region half-offsets (128KB total): R0 = x/cell/y0, R1 = h, R2 = hi, Pl f32
#define R0H 0
#define R1H 16384
#define R2H 32768
#define PLB 98304

typedef _Float16 half8 __attribute__((ext_vector_type(8)));
typedef float f32x4 __attribute__((ext_vector_type(4)));
typedef unsigned u32x4 __attribute__((ext_vector_type(4)));

__device__ __forceinline__ float sigf(float x) { return 1.0f / (1.0f + __expf(-x)); }
__device__ __forceinline__ float tanhf_(float x) {
  float e = __expf(2.0f * x);
  return (e - 1.0f) / (e + 1.0f);
}

__device__ __forceinline__ half8 cvt8(float4 a, float4 b) {
  half8 h;
  h[0] = (_Float16)a.x; h[1] = (_Float16)a.y; h[2] = (_Float16)a.z; h[3] = (_Float16)a.w;
  h[4] = (_Float16)b.x; h[5] = (_Float16)b.y; h[6] = (_Float16)b.z; h[7] = (_Float16)b.w;
  return h;
}

// ---------------- XCD-local barrier (proven); poller wave is a parameter so an
// otherwise-idle wave polls while compute waves fill the window ----------------
__device__ __forceinline__ void gbar_arrive(unsigned* slots, int bc, unsigned epoch) {
  __syncthreads();
  if (threadIdx.x == 0) *(volatile unsigned*)(slots + bc) = epoch;
}

__device__ __forceinline__ void gbar_wait_pw(const unsigned* slots, unsigned epoch,
                                             int pollwave) {
  if ((int)(threadIdx.x >> 6) == pollwave) {
    const volatile unsigned* myslot =
        (const volatile unsigned*)(slots + (threadIdx.x & 31));
    int guard = 0;
    for (;;) {
      asm volatile("buffer_inv sc0\n\ts_waitcnt vmcnt(0)" ::: "memory");
      unsigned v = *myslot;
      if (__ballot(v >= epoch) == ~0ull) break;
      if (++guard > (1 << 14)) break;  // fail loud, not dead
    }
  }
  __syncthreads();
  asm volatile("buffer_inv sc0" ::: "memory");      // L1-only inv; never touches L2
  asm volatile("s_waitcnt vmcnt(0)" ::: "memory");
}

// ---------------- cross-XCD (LLC) primitives — no cache invalidation ----------------
__device__ __forceinline__ unsigned sysld_u32(const unsigned* p) {
  unsigned v;
  asm volatile("global_load_dword %0, %1, off sc0 sc1\n\ts_waitcnt vmcnt(0)"
               : "=v"(v) : "v"(p) : "memory");
  return v;
}

// Raw 32-slot LLC poll, NO closing sync (caller owns the join). Call from ONE wave.
__device__ __forceinline__ void xpoll_raw(const unsigned* slots, unsigned epoch) {
  const unsigned* my = slots + (threadIdx.x & 31);
  int guard = 0;
  for (;;) {
    unsigned v = sysld_u32(my);
    if (__ballot(v >= epoch) == ~0ull) break;
    if (++guard > (1 << 15)) break;  // fail loud, not dead
  }
}

__device__ __forceinline__ void xpost(unsigned* flag, unsigned epoch) {
  asm volatile("s_waitcnt vmcnt(0)" ::: "memory");
  asm volatile("global_store_dword %0, %1, off sc0 sc1" ::
                   "v"(flag), "v"(epoch) : "memory");
}

__device__ __forceinline__ void store_llc_h16(_Float16* p, _Float16 v) {
  unsigned u = (unsigned)__builtin_bit_cast(unsigned short, v);
  asm volatile("global_store_short %0, %1, off sc0 sc1" ::
                   "v"(p), "v"(u) : "memory");
}

// Layer-pipelined persistent nested-LSTM, window-filled schedule.
// Grid 256x256, 1 block/CU. XCD=blockIdx&7; lyr=xcd>>2 (XCDs 0-3 layer 0, 4-7
// layer 1, skewed). pgrp=xcd&3 owns rows [32*pgrp,+32); bc=blockIdx>>3 owns
// gate cols [16bc,+16). Wave K-split: wave wv holds B-frags K [256wv,+256) ->
// waves 0,1 = x/cell half, waves 2,3 = h/hi half. Window filling (identical
// arithmetic to R2, only scheduling):
//  - end window: stage x(t+1) (L0) / LLC-copy y0(t+1) (L1); waves 0,1 run full
//    GEMM1 x-half + Pl writes; wave3 polls end barrier (and L0's bak slots).
//  - cell window: waves 2,3 run full GEMM2 hi-half + Pl writes (hi co-copied
//    with h at step start into R2); wave0 polls cell barrier.
// LDS 128KB: R0 x/cell (32K), R1 h (32K), R2 hi (32K), Pl (32K) — no overlays,
// no overlay syncs. y0 LLC ring deepened 2->4 so L0 leads up to ~3 steps and
// fwd/bak LLC round trips come off the cadence.
__global__ __launch_bounds__(256, 1) void nlstm_pipe(
    const float* __restrict__ xin, const float* __restrict__ h0,
    const float* __restrict__ Wg, const float* __restrict__ bgb,
    const float* __restrict__ Wi, const float* __restrict__ bib,
    float* __restrict__ out, unsigned* __restrict__ bar,
    _Float16* __restrict__ y0buf, _Float16* __restrict__ hlcb,
    _Float16* __restrict__ hicb, _Float16* __restrict__ clcb)
{
  __shared__ __align__(16) char smem[131072];
  _Float16* AldsH = (_Float16*)smem;
  float* Pl = (float*)(smem + PLB);

  const int tid  = threadIdx.x;
  const int xcd  = blockIdx.x & 7;
  const int lyr  = xcd >> 2;
  const int pgrp = xcd & 3;
  const int bc   = blockIdx.x >> 3;
  const int wv   = tid >> 6;
  const int lane = tid & 63;
  const int ln   = lane & 15;
  const int kg   = lane >> 4;
  const int pb   = tid >> 4;
  const int pj   = tid & 15;
  const int jglob = bc * 16 + pj;
  const int ncol  = bc * 16 + ln;
  const int r0    = pgrp * 32;

  const int exo = (jglob >> 5) * 1024 + (((jglob >> 3) & 3) * 16 + pb) * 8 + (jglob & 7);

  unsigned* eslots = bar + xcd * 64;       // 32 end slots (local)
  unsigned* cslots = eslots + 32;          // 32 cell slots (local)
  unsigned* fwdS = bar + 512 + pgrp * 32;  // 32 per-block fwd slots (LLC)
  unsigned* bakS = bar + 640 + pgrp * 32;  // 32 per-block back slots (LLC)

  _Float16* hloc0 = hlcb + ((size_t)xcd * 2 + 0) * 16384;
  _Float16* hloc1 = hlcb + ((size_t)xcd * 2 + 1) * 16384;
  _Float16* hilc0 = hicb + ((size_t)xcd * 2 + 0) * 16384;
  _Float16* hilc1 = hicb + ((size_t)xcd * 2 + 1) * 16384;
  _Float16* cbase = clcb + (size_t)xcd * 16384;
  _Float16* y0base = y0buf + (size_t)pgrp * 4 * 16384;  // 4-deep ring

  // ---- weights -> VGPR fp16 frags ----
  half8 wgf[4][8], wif[4][8];
  float bgv[4], biv[4];
#pragma unroll
  for (int g = 0; g < 4; ++g) {
    const float* wgr = Wg + ((size_t)lyr * 2048 + g * 512 + ncol) * 1024 + wv * 256;
    const float* wir = Wi + ((size_t)lyr * 2048 + g * 512 + ncol) * 1024 + wv * 256;
#pragma unroll
    for (int i = 0; i < 8; ++i) {
      const float* p = wgr + i * 32 + kg * 8;
      wgf[g][i] = cvt8(*(const float4*)p, *(const float4*)(p + 4));
      const float* q = wir + i * 32 + kg * 8;
      wif[g][i] = cvt8(*(const float4*)q, *(const float4*)(q + 4));
    }
    bgv[g] = bgb[lyr * 2048 + g * 512 + jglob];
    biv[g] = bib[lyr * 2048 + g * 512 + jglob];
  }

  // ---- initial states (rows pb, pb+16) ----
  float st_c[2], st_ci[2], o_pre[2];
  {
    const float* h0l = h0 + (size_t)lyr * 4 * B_DIM * H_DIM + (size_t)(r0 + pb) * H_DIM + jglob;
#pragma unroll
    for (int mt = 0; mt < 2; ++mt) {
      const float* pp = h0l + (size_t)mt * 16 * H_DIM;
      float h_in  = pp[0];
      st_c[mt]    = pp[(size_t)1 * B_DIM * H_DIM];
      float hi_in = pp[(size_t)2 * B_DIM * H_DIM];
      st_ci[mt]   = pp[(size_t)3 * B_DIM * H_DIM];
      hloc0[exo + mt * 512] = (_Float16)h_in;
      hilc0[exo + mt * 512] = (_Float16)hi_in;
      o_pre[mt] = 0.f;
    }
  }

  // ---- helpers ----
  auto stage_x = [&](int t) {  // layer 0 only: xin(t) -> R0
    const int m = tid & 31;
    const int q = tid >> 5;
    const int mt = m >> 4, mm = m & 15;
    const float* srow = xin + ((size_t)t * B_DIM + r0 + m) * C_DIM;
#pragma unroll
    for (int i = 0; i < 8; ++i) {
      const int chunk = q * 8 + i;
      const int ks = chunk >> 2, kq = chunk & 3;
      const float* p = srow + chunk * 8;
      *(half8*)(AldsH + R0H + ks * 1024 + mt * 512 + (kq * 16 + mm) * 8) =
          cvt8(*(const float4*)p, *(const float4*)(p + 4));
    }
  };
  auto copy_hhi = [&](const _Float16* hrd, const _Float16* hird) {  // 64KB, 16 loads in flight
    u32x4 vh[8], vy[8];
#pragma unroll
    for (int i = 0; i < 8; ++i) vh[i] = *(const u32x4*)(hrd + (i * 256 + tid) * 8);
#pragma unroll
    for (int i = 0; i < 8; ++i) vy[i] = *(const u32x4*)(hird + (i * 256 + tid) * 8);
#pragma unroll
    for (int i = 0; i < 8; ++i) *(u32x4*)(AldsH + R1H + (i * 256 + tid) * 8) = vh[i];
#pragma unroll
    for (int i = 0; i < 8; ++i) *(u32x4*)(AldsH + R2H + (i * 256 + tid) * 8) = vy[i];
  };
  auto copy_r0 = [&](const _Float16* src) {  // 32KB local slab -> R0
    u32x4 v[8];
#pragma unroll
    for (int i = 0; i < 8; ++i) v[i] = *(const u32x4*)(src + (i * 256 + tid) * 8);
#pragma unroll
    for (int i = 0; i < 8; ++i) *(u32x4*)(AldsH + R0H + (i * 256 + tid) * 8) = v[i];
  };
  auto copy_r0_sys = [&](const _Float16* src) {  // 32KB LLC slab -> R0
    u32x4 v[8];
#pragma unroll
    for (int i = 0; i < 8; ++i) {
      const u32x4* p = (const u32x4*)(src + (i * 256 + tid) * 8);
      asm volatile("global_load_dwordx4 %0, %1, off sc0 sc1"
                   : "=v"(v[i]) : "v"(p) : "memory");
    }
    asm volatile("s_waitcnt vmcnt(0)" ::: "memory");
    __builtin_amdgcn_sched_barrier(0);
#pragma unroll
    for (int i = 0; i < 8; ++i)
      *(u32x4*)(AldsH + R0H + (i * 256 + tid) * 8) = v[i];
  };
  auto mfma8 = [&](const _Float16* rb, int ksb, half8 (&wf)[4][8], f32x4 (&acc)[2][4]) {
#pragma unroll
    for (int i = 0; i < 8; ++i) {
      const _Float16* ab = rb + (ksb + i) * 1024 + lane * 8;
      half8 a0 = *(const half8*)(ab);
      half8 a1 = *(const half8*)(ab + 512);
#pragma unroll
      for (int g = 0; g < 4; ++g) {
        acc[0][g] = __builtin_amdgcn_mfma_f32_16x16x32_f16(a0, wf[g][i], acc[0][g], 0, 0, 0);
        acc[1][g] = __builtin_amdgcn_mfma_f32_16x16x32_f16(a1, wf[g][i], acc[1][g], 0, 0, 0);
      }
    }
  };
  auto plw = [&](f32x4 (&acc)[2][4]) {
#pragma unroll
    for (int mt = 0; mt < 2; ++mt)
#pragma unroll
      for (int g = 0; g < 4; ++g)
#pragma unroll
        for (int rr = 0; rr < 4; ++rr)
          Pl[(((g * 2 + mt) * 16 + kg * 4 + rr) * 16 + ln) * 4 + (wv ^ kg)] = acc[mt][g][rr];
  };
  auto plsum = [&](int g, int mt) -> float {
    f32x4 v = *(const f32x4*)(Pl + (((g * 2 + mt) * 16 + pb) * 16 + pj) * 4);
    return v[0] + v[1] + v[2] + v[3];
  };

  unsigned eseq = 0, cseq = 0;

  // ---- init publish + x(0)/y0(0) staging + early GEMM1(0) ----
  gbar_arrive(eslots, bc, ++eseq);
  if (lyr == 0) stage_x(0);
  gbar_wait_pw(eslots, eseq, 3);
  if (lyr == 1) {
    if (wv == 0) xpoll_raw(fwdS, 1u);  // all 32 L0 blocks finished step 0
    __syncthreads();
    copy_r0_sys(y0base + 0);           // y0(0) in ring slot 0
    __syncthreads();
    if (tid == 0) xpost(bakS + bc, 1u);
  }
  if (wv < 2) {  // GEMM1(0) x-half
    f32x4 acc[2][4];
#pragma unroll
    for (int mt = 0; mt < 2; ++mt)
#pragma unroll
      for (int g = 0; g < 4; ++g) acc[mt][g] = (f32x4){0.f, 0.f, 0.f, 0.f};
    mfma8(AldsH + R0H, 8 * wv, wgf, acc);
    plw(acc);
  }

  for (int t = 0; t < T_DIM; ++t) {
    const int pr = t & 1;
    _Float16* hrd  = pr ? hloc1 : hloc0;
    _Float16* hwr  = pr ? hloc0 : hloc1;
    _Float16* hird = pr ? hilc1 : hilc0;
    _Float16* hiwr = pr ? hilc0 : hilc1;
    _Float16* y0wr = y0base + (size_t)(t & 3) * 16384;        // L0 writes y0(t)
    _Float16* y0rd = y0base + (size_t)((t + 1) & 3) * 16384;  // L1 end window reads y0(t+1)

    // ---- stage h(t-1)->R1, hi(t-1)->R2 (single MLP'd 64KB copy) ----
    copy_hhi(hrd, hird);
    __syncthreads();

    // ---- GEMM1 h-half (waves 2,3); waves 0,1 Pl already written in end window ----
    if (wv >= 2) {
      f32x4 acc[2][4];
#pragma unroll
      for (int mt = 0; mt < 2; ++mt)
#pragma unroll
        for (int g = 0; g < 4; ++g) acc[mt][g] = (f32x4){0.f, 0.f, 0.f, 0.f};
      mfma8(AldsH + R1H, 8 * wv - 16, wgf, acc);
      plw(acc);
    }
    __syncthreads();

    // ---- pointwise 1: cell = sig(f)*c + sig(i)*tanh(gc) ----
#pragma unroll
    for (int mt = 0; mt < 2; ++mt) {
      float gi = plsum(0, mt) + bgv[0];
      float gf = plsum(1, mt) + bgv[1];
      float go = plsum(2, mt) + bgv[2];
      float gc = plsum(3, mt) + bgv[3];
      float cell = sigf(gf) * st_c[mt] + sigf(gi) * tanhf_(gc);
      o_pre[mt] = go;
      cbase[exo + mt * 512] = (_Float16)cell;
    }
    gbar_arrive(cslots, bc, ++cseq);
    // ---- cell window: waves 2,3 run GEMM2 hi-half + Pl; wave0 polls ----
    if (wv >= 2) {
      f32x4 acc[2][4];
#pragma unroll
      for (int mt = 0; mt < 2; ++mt)
#pragma unroll
        for (int g = 0; g < 4; ++g) acc[mt][g] = (f32x4){0.f, 0.f, 0.f, 0.f};
      mfma8(AldsH + R2H, 8 * wv - 16, wif, acc);
      plw(acc);
    }
    gbar_wait_pw(cslots, cseq, 0);  // cell visible XCD-wide

    copy_r0(cbase);  // stage cell -> R0
    __syncthreads();

    // ---- GEMM2 cell-half (waves 0,1) ----
    if (wv < 2) {
      f32x4 acc[2][4];
#pragma unroll
      for (int mt = 0; mt < 2; ++mt)
#pragma unroll
        for (int g = 0; g < 4; ++g) acc[mt][g] = (f32x4){0.f, 0.f, 0.f, 0.f};
      mfma8(AldsH + R0H, 8 * wv, wif, acc);
      plw(acc);
    }
    __syncthreads();

    // ---- pointwise 2: inner cell; outputs; c := hi_n ----
#pragma unroll
    for (int mt = 0; mt < 2; ++mt) {
      float i2 = plsum(0, mt) + biv[0];
      float f2 = plsum(1, mt) + biv[1];
      float o2 = plsum(2, mt) + biv[2];
      float c2 = plsum(3, mt) + biv[3];
      float ci_n = sigf(f2) * st_ci[mt] + sigf(i2) * tanhf_(c2);
      float hi_n = sigf(o2) * tanhf_(ci_n);
      float h_n  = sigf(o_pre[mt]) * tanhf_(hi_n);
      st_ci[mt] = ci_n;
      st_c[mt]  = hi_n;  // reference carry: c <- hi_n
      hiwr[exo + mt * 512] = (_Float16)hi_n;
      hwr[exo + mt * 512]  = (_Float16)h_n;
      if (lyr == 0) {
        store_llc_h16(y0wr + exo + mt * 512, (_Float16)h_n);
      } else {
        out[((size_t)t * B_DIM + (r0 + pb + mt * 16)) * H_DIM + jglob] = h_n;
      }
    }

    gbar_arrive(eslots, bc, ++eseq);  // end barrier: arrive (drains y0 stores)
    // ---- end window ----
    if (lyr == 0) {
      if (tid == 0) xpost(fwdS + bc, (unsigned)(t + 1));  // unblock L1 first
      if (t + 1 < T_DIM) {
        stage_x(t + 1);
        __syncthreads();
        if (wv < 2) {  // early GEMM1(t+1) x-half
          f32x4 acc[2][4];
#pragma unroll
          for (int mt = 0; mt < 2; ++mt)
#pragma unroll
            for (int g = 0; g < 4; ++g) acc[mt][g] = (f32x4){0.f, 0.f, 0.f, 0.f};
          mfma8(AldsH + R0H, 8 * wv, wgf, acc);
          plw(acc);
        } else if (wv == 3 && t >= 2) {
          // ring clearance for step t+1's slab ((t+1)&3, holds y0(t-3)):
          // all L1 blocks consumed it when bak >= t-2. Overlaps end poll.
          xpoll_raw(bakS, (unsigned)(t - 2));
        }
      }
    } else if (t + 1 < T_DIM) {
      if (wv == 0) xpoll_raw(fwdS, (unsigned)(t + 2));  // L0 past step t+1
      __syncthreads();
      copy_r0_sys(y0rd);  // x(t+1) = y0(t+1)
      __syncthreads();
      if (tid == 0) xpost(bakS + bc, (unsigned)(t + 2));  // consumed y0(t+1)
      if (wv < 2) {  // early GEMM1(t+1) x-half
        f32x4 acc[2][4];
#pragma unroll
        for (int mt = 0; mt < 2; ++mt)
#pragma unroll
          for (int g = 0; g < 4; ++g) acc[mt][g] = (f32x4){0.f, 0.f, 0.f, 0.f};
        mfma8(AldsH + R0H, 8 * wv, wgf, acc);
        plw(acc);
      }
    }
    gbar_wait_pw(eslots, eseq, 3);  // wave3 polls; h/hi visible for next step
  }
}

extern "C" void kernel_launch(void* const* d_in, const int* in_sizes, int n_in,
                              void* d_out, int out_size, void* d_ws, size_t ws_size,
                              hipStream_t stream) {
  const float* xin = (const float*)d_in[0];
  const float* h0  = (const float*)d_in[1];
  const float* Wg  = (const float*)d_in[2];
  const float* bg  = (const float*)d_in[3];
  const float* Wi  = (const float*)d_in[4];
  const float* bi  = (const float*)d_in[5];
  float* out = (float*)d_out;

  // ws layout:
  //   [0,4KB)  flags: 8 XCD x 64 local (2KB) | fwd 4x32 @ +512 | back 4x32 @ +640
  //   y0buf  [4 pair][4 ring][16384] fp16 = 512KB  (LLC cross-layer feed)
  //   hlcb   [8 xcd][2 parity][16384] fp16 = 512KB
  //   hicb   [8 xcd][2 parity][16384] fp16 = 512KB
  //   clcb   [8 xcd][16384] fp16 = 256KB
  unsigned* bar  = (unsigned*)d_ws;
  _Float16* y0b  = (_Float16*)((char*)d_ws + 4096);
  _Float16* hlcb = y0b + (size_t)4 * 4 * 16384;
  _Float16* hicb = hlcb + (size_t)8 * 2 * 16384;
  _Float16* clcb = hicb + (size_t)8 * 2 * 16384;

  hipMemsetAsync(d_ws, 0, 4096, stream);  // all flag epochs start at 0

  nlstm_pipe<<<dim3(256), dim3(256), 0, stream>>>(
      xin, h0, Wg, bg, Wi, bi, out, bar, y0b, hlcb, hicb, clcb);
}